// Round 1
// baseline (1268.091 us; speedup 1.0000x reference)
//
#include <hip/hip_runtime.h>

// Problem constants
#define BN 8          // batch
#define CS 128        // student channels
#define CT 256        // teacher channels
#define HH 64
#define WW 64
#define HW 4096       // 64*64
#define PH 66         // padded
#define PW 66
#define PPLANE (PH*PW)       // 4356
// ws layout (floats):
//   masked_padded: [BN][CT][PPLANE] at 0
//   t1_padded:     [BN][CT][PPLANE] at MASKED_ELEMS
//   accums:        pp[8] | tt[8] | pt[8][8]  (80 floats) at 2*MASKED_ELEMS
#define MASKED_ELEMS ((size_t)BN * CT * PPLANE)   // 8,921,088

// ---------------------------------------------------------------------------
// K1: 1x1 conv (align) + checkerboard mask, writes into padded layout.
// grid = BN*CT*16 blocks of 256; each block: one (n, co), 256 pixels.
// ---------------------------------------------------------------------------
__global__ __launch_bounds__(256) void k1_conv1x1_mask(
    const float* __restrict__ pS, const float* __restrict__ Wa,
    const float* __restrict__ ba, float* __restrict__ masked)
{
  __shared__ float wl[CS];
  int b  = blockIdx.x;
  int pb = b & 15;
  int co = (b >> 4) & (CT - 1);
  int n  = b >> 12;
  int t  = threadIdx.x;
  if (t < CS) wl[t] = Wa[co * CS + t];
  __syncthreads();

  int pix = pb * 256 + t;
  int h = pix >> 6, w = pix & 63;
  const float* sp = pS + (((size_t)n * CS) << 12) + pix;
  float acc = 0.f;
  #pragma unroll 8
  for (int ci = 0; ci < CS; ++ci)
    acc += sp[(size_t)ci << 12] * wl[ci];
  acc += ba[co];
  float mat = (float)((h + w) & 1);   // checkerboard
  masked[((size_t)(n * CT + co)) * PPLANE + (size_t)(h + 1) * PW + (w + 1)] = acc * mat;
}

// ---------------------------------------------------------------------------
// K2: direct 3x3 conv, padded in/out. 256 threads: w = t&63, hq = t>>6.
// Each block: fixed n, 4 output channels (co0..co0+3), 16 h rows (h0..h0+15),
// 64 w. Each thread: 4 h (hb..hb+3) x 4 co accumulators.
// MODE 0: + bias, relu, write padded out (gen1)
// MODE 1: + bias, fused reduction: tt[n] += v^2, pt[i][n] += v * pT[i] (gen2)
// grid = BN * 4 * 64 = 2048 blocks.
// ---------------------------------------------------------------------------
template <int MODE>
__global__ __launch_bounds__(256) void k2_conv3x3(
    const float* __restrict__ in, const float* __restrict__ Wg,
    const float* __restrict__ bg, float* __restrict__ out,
    const float* __restrict__ pT, float* __restrict__ accums)
{
  __shared__ float wl[4 * CT * 9];   // 36,864 B: weights for 4 co
  __shared__ float red[256];

  int b  = blockIdx.x;
  int cg = b & 63;
  int ht = (b >> 6) & 3;
  int n  = b >> 8;
  int t  = threadIdx.x;
  int w  = t & 63;
  int hq = t >> 6;
  int co0 = cg * 4;
  int h0  = ht * 16;
  int hb  = h0 + hq * 4;   // first output row for this thread

  for (int i = t; i < 4 * CT * 9; i += 256)
    wl[i] = Wg[(size_t)co0 * (CT * 9) + i];
  __syncthreads();

  float acc[4][4];
  #pragma unroll
  for (int j = 0; j < 4; ++j)
    #pragma unroll
    for (int k = 0; k < 4; ++k) acc[j][k] = 0.f;

  const float* ibase = in + (size_t)n * CT * PPLANE;
  for (int ci = 0; ci < CT; ++ci) {
    const float* ip = ibase + (size_t)ci * PPLANE;
    float iv[6][3];
    #pragma unroll
    for (int rr = 0; rr < 6; ++rr) {
      // padded row index for input row (hb-1+rr) is (hb+rr); padded col for
      // input col (w-1+dc) is (w+dc).
      const float* rp = ip + (size_t)(hb + rr) * PW + w;
      iv[rr][0] = rp[0]; iv[rr][1] = rp[1]; iv[rr][2] = rp[2];
    }
    #pragma unroll
    for (int k = 0; k < 4; ++k) {
      const float* wk = wl + (k * CT + ci) * 9;
      #pragma unroll
      for (int r = 0; r < 3; ++r)
        #pragma unroll
        for (int dc = 0; dc < 3; ++dc) {
          float wv = wk[r * 3 + dc];
          #pragma unroll
          for (int j = 0; j < 4; ++j)
            acc[j][k] += iv[j + r][dc] * wv;
        }
    }
  }

  if (MODE == 0) {
    #pragma unroll
    for (int k = 0; k < 4; ++k) {
      float bias = bg[co0 + k];
      #pragma unroll
      for (int j = 0; j < 4; ++j) {
        float v = acc[j][k] + bias;
        v = fmaxf(v, 0.f);   // relu
        out[((size_t)(n * CT + co0 + k)) * PPLANE + (size_t)(hb + j + 1) * PW + (w + 1)] = v;
      }
    }
  } else {
    float tt = 0.f;
    float pt[8];
    #pragma unroll
    for (int i = 0; i < 8; ++i) pt[i] = 0.f;
    #pragma unroll
    for (int k = 0; k < 4; ++k) {
      float bias = bg[co0 + k];
      #pragma unroll
      for (int j = 0; j < 4; ++j) {
        float v = acc[j][k] + bias;
        tt += v * v;
        int pix = ((hb + j) << 6) + w;
        #pragma unroll
        for (int i = 0; i < 8; ++i)
          pt[i] += v * pT[(((size_t)(i * CT + co0 + k)) << 12) + pix];
      }
    }
    // block reduction of 9 values, one atomicAdd each
    float vals[9];
    vals[0] = tt;
    #pragma unroll
    for (int i = 0; i < 8; ++i) vals[i + 1] = pt[i];
    for (int q = 0; q < 9; ++q) {
      red[t] = vals[q];
      __syncthreads();
      for (int s = 128; s > 0; s >>= 1) {
        if (t < s) red[t] += red[t + s];
        __syncthreads();
      }
      if (t == 0) {
        int idx = (q == 0) ? (8 + n) : (16 + (q - 1) * 8 + n);
        atomicAdd(&accums[idx], red[0]);
      }
      __syncthreads();
    }
  }
}

// ---------------------------------------------------------------------------
// K3: pp[n] = ||preds_T[n]||^2. grid = 8*32 blocks of 256, float4 loads.
// ---------------------------------------------------------------------------
__global__ __launch_bounds__(256) void k3_pp(
    const float* __restrict__ pT, float* __restrict__ accums)
{
  __shared__ float red[256];
  int n  = blockIdx.x >> 5;
  int cb = blockIdx.x & 31;
  int t  = threadIdx.x;
  const float4* p4 = (const float4*)(pT + ((size_t)n << 20));
  // 2^20 floats per n = 262144 float4; 32 blocks -> 8192 float4 per block
  float s = 0.f;
  int base = cb * 8192;
  for (int i = base + t; i < base + 8192; i += 256) {
    float4 v = p4[i];
    s += v.x * v.x + v.y * v.y + v.z * v.z + v.w * v.w;
  }
  red[t] = s;
  __syncthreads();
  for (int st = 128; st > 0; st >>= 1) {
    if (t < st) red[t] += red[t + st];
    __syncthreads();
  }
  if (t == 0) atomicAdd(&accums[n], red[0]);
}

// ---------------------------------------------------------------------------
// K4: finisher. sq[i][j] = pp[i] + tt[j] - 2 pt[i][j]; logits = -sq/128;
// ce = mean_i(logsumexp_j - diag); loss = ce * 16 * 2e-5.
// ---------------------------------------------------------------------------
__global__ void k4_final(const float* __restrict__ accums, float* __restrict__ out)
{
  if (threadIdx.x == 0 && blockIdx.x == 0) {
    double logits[8][8];
    for (int i = 0; i < 8; ++i)
      for (int j = 0; j < 8; ++j) {
        double sq = (double)accums[i] + (double)accums[8 + j]
                    - 2.0 * (double)accums[16 + i * 8 + j];
        logits[i][j] = -0.5 * sq / 64.0;
      }
    double ce = 0.0;
    for (int i = 0; i < 8; ++i) {
      double m = logits[i][0];
      for (int j = 1; j < 8; ++j) m = logits[i][j] > m ? logits[i][j] : m;
      double s = 0.0;
      for (int j = 0; j < 8; ++j) s += exp(logits[i][j] - m);
      double lse = m + log(s);
      ce += lse - logits[i][i];
    }
    ce /= 8.0;
    double loss = ce * (2.0 * 64.0) / 8.0 * 2e-5;
    out[0] = (float)loss;
  }
}

// ---------------------------------------------------------------------------
extern "C" void kernel_launch(void* const* d_in, const int* in_sizes, int n_in,
                              void* d_out, int out_size, void* d_ws, size_t ws_size,
                              hipStream_t stream)
{
  const float* preds_S = (const float*)d_in[0];
  const float* preds_T = (const float*)d_in[1];
  const float* W_align = (const float*)d_in[2];
  const float* b_align = (const float*)d_in[3];
  const float* W_gen1  = (const float*)d_in[4];
  const float* b_gen1  = (const float*)d_in[5];
  const float* W_gen2  = (const float*)d_in[6];
  const float* b_gen2  = (const float*)d_in[7];
  float* out = (float*)d_out;

  float* ws     = (float*)d_ws;
  float* masked = ws;
  float* t1     = ws + MASKED_ELEMS;
  float* accums = ws + 2 * MASKED_ELEMS;

  // zero padded buffers (borders must be 0) + accumulators; ws is poisoned
  // before every timed launch.
  size_t zero_bytes = (2 * MASKED_ELEMS + 80) * sizeof(float);
  hipMemsetAsync(d_ws, 0, zero_bytes, stream);

  k1_conv1x1_mask<<<BN * CT * 16, 256, 0, stream>>>(preds_S, W_align, b_align, masked);
  k2_conv3x3<0><<<BN * 4 * 64, 256, 0, stream>>>(masked, W_gen1, b_gen1, t1, nullptr, nullptr);
  k2_conv3x3<1><<<BN * 4 * 64, 256, 0, stream>>>(t1, W_gen2, b_gen2, nullptr, preds_T, accums);
  k3_pp<<<BN * 32, 256, 0, stream>>>(preds_T, accums);
  k4_final<<<1, 64, 0, stream>>>(accums, out);
}

// Round 2
// 564.254 us; speedup vs baseline: 2.2474x; 2.2474x over previous
//
#include <hip/hip_runtime.h>

typedef unsigned short u16;
typedef short short8 __attribute__((ext_vector_type(8)));
typedef float floatx16 __attribute__((ext_vector_type(16)));

// ---- sizes (ushort units unless noted) ----
// masked2/t1/t2 layout: [n 8][cg 16][half 2][r 66][c 66][j 8] bf16
#define PLANE8   34848          // 66*66*8
#define NSTRIDE  1115136        // 16*2*PLANE8
#define BUF_B    17842176       // NSTRIDE*8*2 bytes
// Wsw layout: [cg 16][ct 4][d 1152][j 8] bf16 ; d = tap*128 + sc*64 + cihalf*32 + colow
#define WSW_B    1179648        // 16*4*1152*8*2 bytes

__device__ __forceinline__ u16 f2b(float f) {
  unsigned u = __builtin_bit_cast(unsigned, f);
  return (u16)((u + 0x7FFFu + ((u >> 16) & 1u)) >> 16);
}
__device__ __forceinline__ float b2f(u16 b) {
  return __builtin_bit_cast(float, ((unsigned)b) << 16);
}

typedef const __attribute__((address_space(1))) unsigned int* gptr_t;
typedef __attribute__((address_space(3))) unsigned int* sptr_t;

// ---------------------------------------------------------------------------
// k1: 1x1 conv + checkerboard mask (fp32 math), writes swizzled bf16 layout.
// grid 8192 = n(8) x co(256) x pixblock(4); thread: 4 consecutive pixels.
// ---------------------------------------------------------------------------
__global__ __launch_bounds__(256) void k1(const float* __restrict__ pS,
    const float* __restrict__ Wa, const float* __restrict__ ba,
    u16* __restrict__ mk)
{
  __shared__ float wl[128];
  int b = blockIdx.x;
  int pb = b & 3, co = (b >> 2) & 255, n = b >> 10;
  int t = threadIdx.x;
  if (t < 128) wl[t] = Wa[co * 128 + t];
  __syncthreads();
  int p = pb * 1024 + t * 4;
  const float* sp = pS + ((size_t)n * 128) * 4096 + p;
  float a0 = 0.f, a1 = 0.f, a2 = 0.f, a3 = 0.f;
  for (int ci = 0; ci < 128; ++ci) {
    float4 s = *(const float4*)(sp + (size_t)ci * 4096);
    float wv = wl[ci];
    a0 += s.x * wv; a1 += s.y * wv; a2 += s.z * wv; a3 += s.w * wv;
  }
  float bias = ba[co];
  int cg = co >> 4, hf = (co >> 3) & 1, j = co & 7;
  u16* base = mk + (size_t)n * NSTRIDE + (size_t)(cg * 2 + hf) * PLANE8;
  float av[4] = {a0, a1, a2, a3};
  #pragma unroll
  for (int k = 0; k < 4; ++k) {
    int pp = p + k; int h = pp >> 6, w = pp & 63;
    float v = (av[k] + bias) * (float)((h + w) & 1);
    base[((h + 1) * 66 + (w + 1)) * 8 + j] = f2b(v);
  }
}

// ---------------------------------------------------------------------------
// kwc: convert/swizzle 3x3 weights fp32 [co][ci][3][3] -> Wsw bf16.
// grid 288 x 256 covers 73728 16B-chunks.
// ---------------------------------------------------------------------------
__global__ __launch_bounds__(256) void kwc(const float* __restrict__ W,
                                           u16* __restrict__ D)
{
  int cid = blockIdx.x * 256 + threadIdx.x;        // < 73728
  int d = cid % 1152, ctcg = cid / 1152;
  int ct = ctcg & 3, cg = ctcg >> 2;
  int colow = d & 31, cihalf = (d >> 5) & 1, sc = (d >> 6) & 1, tap = d >> 7;
  int co = ct * 64 + sc * 32 + colow;
  short8 v;
  #pragma unroll
  for (int jj = 0; jj < 8; ++jj) {
    int ci = cg * 16 + cihalf * 8 + jj;
    v[jj] = (short)f2b(W[((size_t)(co * 256 + ci)) * 9 + tap]);
  }
  *(short8*)&D[(size_t)cid * 8] = v;
}

// ---------------------------------------------------------------------------
// kconv: 3x3 conv 256->256 via bf16 MFMA implicit GEMM.
// grid 1024 = n(8) x ct(4) x rowtile(32); block 128 threads = 2 waves.
// Block tile: co 64 x (2 rows x 64 cols). Wave w: output row h0+w,
// 2x2 subtiles of 32co x 32pix. K-loop: 16 ci-chunks x 9 taps.
// A-operand = input (m=pix), B = weights (n=co) -> D cols = co (coalesced
// bf16 stores into swizzled layout).
// ---------------------------------------------------------------------------
template <int RELU>
__global__ __launch_bounds__(128) void kconv(
    const u16* __restrict__ IN, const u16* __restrict__ WS,
    const float* __restrict__ bg, u16* __restrict__ OUT)
{
  __shared__ __align__(16) u16 Lin[2 * 4 * 66 * 8];   //  8448 B
  __shared__ __align__(16) u16 Lw[1152 * 8];          // 18432 B

  int b = blockIdx.x;
  int rt = b & 31, ct = (b >> 5) & 3, n = b >> 7;
  int h0 = rt * 2;
  int t = threadIdx.x;
  int wid = t >> 6, lane = t & 63;
  int hf = lane >> 5, ml = lane & 31;

  // --- precompute in-staging per-thread global offsets (ushort units) ---
  // chunks d in [0,528): d = (half*4 + rr)*66 + c ; LDS dest = d*8 ushorts
  int in_goff[5];
  #pragma unroll
  for (int k = 0; k < 5; ++k) {
    int sidx = wid + 2 * k;
    int d = sidx * 64 + lane;
    if (sidx < 9 && d < 528) {
      int ihalf = d / 264, rem = d - ihalf * 264;
      int rr = rem / 66, c = rem - rr * 66;
      in_goff[k] = ihalf * PLANE8 + ((h0 + rr) * 66 + c) * 8;
    } else in_goff[k] = -1;
  }

  const u16* inb = IN + (size_t)n * NSTRIDE;
  const u16* wg  = WS + (size_t)ct * 1152 * 8;

  floatx16 acc00, acc01, acc10, acc11;
  #pragma unroll
  for (int i = 0; i < 16; ++i) { acc00[i] = 0.f; acc01[i] = 0.f; acc10[i] = 0.f; acc11[i] = 0.f; }

  const short8* LinV = (const short8*)Lin;
  const short8* LwV  = (const short8*)Lw;

  for (int cg = 0; cg < 16; ++cg) {
    // ---- stage weights: 18 wave-segs (9 per wave), contiguous 1KB each ----
    #pragma unroll
    for (int k = 0; k < 9; ++k) {
      int sidx = wid + 2 * k;
      const u16* src = wg + (size_t)cg * 36864 + (size_t)(sidx * 64 + lane) * 8;
      __builtin_amdgcn_global_load_lds((gptr_t)(const void*)src,
                                       (sptr_t)(void*)(Lw + sidx * 512), 16, 0, 0);
    }
    // ---- stage input tile: 9 wave-segs ----
    #pragma unroll
    for (int k = 0; k < 5; ++k) {
      if (in_goff[k] >= 0) {
        int sidx = wid + 2 * k;
        const u16* src = inb + (size_t)cg * 69696 + in_goff[k];
        __builtin_amdgcn_global_load_lds((gptr_t)(const void*)src,
                                         (sptr_t)(void*)(Lin + sidx * 512), 16, 0, 0);
      }
    }
    __syncthreads();

    // ---- 9 taps x 4 MFMA ----
    #pragma unroll
    for (int dr = 0; dr < 3; ++dr) {
      int rbase = (hf * 4 + (wid + dr)) * 66;
      #pragma unroll
      for (int dc = 0; dc < 3; ++dc) {
        int tap = dr * 3 + dc;
        short8 w0 = LwV[(tap * 2 + 0) * 64 + lane];
        short8 w1 = LwV[(tap * 2 + 1) * 64 + lane];
        short8 i0 = LinV[rbase + ml + dc];
        short8 i1 = LinV[rbase + 32 + ml + dc];
        acc00 = __builtin_amdgcn_mfma_f32_32x32x16_bf16(i0, w0, acc00, 0, 0, 0);
        acc01 = __builtin_amdgcn_mfma_f32_32x32x16_bf16(i0, w1, acc01, 0, 0, 0);
        acc10 = __builtin_amdgcn_mfma_f32_32x32x16_bf16(i1, w0, acc10, 0, 0, 0);
        acc11 = __builtin_amdgcn_mfma_f32_32x32x16_bf16(i1, w1, acc11, 0, 0, 0);
      }
    }
    __syncthreads();
  }

  // ---- epilogue: bias (+relu), store bf16 swizzled ----
  int co0 = ct * 64 + ml, co1 = co0 + 32;
  float bias0 = bg[co0], bias1 = bg[co1];
  int sb0 = ((co0 >> 4) * 2 + ((co0 >> 3) & 1)) * PLANE8 + ((h0 + wid + 1) * 66 + 1) * 8 + (co0 & 7);
  int sb1 = ((co1 >> 4) * 2 + ((co1 >> 3) & 1)) * PLANE8 + ((h0 + wid + 1) * 66 + 1) * 8 + (co1 & 7);
  u16* ob = OUT + (size_t)n * NSTRIDE;
  #pragma unroll
  for (int reg = 0; reg < 16; ++reg) {
    int m = (reg & 3) + 8 * (reg >> 2) + 4 * hf;
    float v;
    v = acc00[reg] + bias0; if (RELU) v = fmaxf(v, 0.f); ob[sb0 + m * 8] = f2b(v);
    v = acc01[reg] + bias1; if (RELU) v = fmaxf(v, 0.f); ob[sb1 + m * 8] = f2b(v);
    v = acc10[reg] + bias0; if (RELU) v = fmaxf(v, 0.f); ob[sb0 + (32 + m) * 8] = f2b(v);
    v = acc11[reg] + bias1; if (RELU) v = fmaxf(v, 0.f); ob[sb1 + (32 + m) * 8] = f2b(v);
  }
}

// ---------------------------------------------------------------------------
// kbmc: fused reduction. pp[i]=||pT_i||^2, tt[n]=||t2_n||^2, pt[i][n]=pT_i.t2_n
// grid 512 = cg(16) x half(2) x r4(16); 256 thr = 4 waves (wave = n-pair).
// ---------------------------------------------------------------------------
__global__ __launch_bounds__(256) void kbmc(const u16* __restrict__ t2,
    const float* __restrict__ pT, float* __restrict__ accums)
{
  int b = blockIdx.x;
  int r4 = b & 15, hf = (b >> 4) & 1, cg = b >> 5;
  int t = threadIdx.x, c = t & 63, ng = t >> 6;
  float pt[2][8], tt[2], pp[8];
  #pragma unroll
  for (int i = 0; i < 8; ++i) { pt[0][i] = 0.f; pt[1][i] = 0.f; pp[i] = 0.f; }
  tt[0] = 0.f; tt[1] = 0.f;

  for (int rr = 0; rr < 4; ++rr) {
    int r = r4 * 4 + rr;
    float tv[2][8];
    #pragma unroll
    for (int k = 0; k < 2; ++k) {
      int n = ng * 2 + k;
      const u16* tp = t2 + (size_t)n * NSTRIDE + (size_t)(cg * 2 + hf) * PLANE8
                      + ((r + 1) * 66 + (c + 1)) * 8;
      short8 v = *(const short8*)tp;
      #pragma unroll
      for (int jj = 0; jj < 8; ++jj) tv[k][jj] = b2f((u16)v[jj]);
    }
    int pix = r * 64 + c;
    #pragma unroll
    for (int j = 0; j < 8; ++j) {
      int co = cg * 16 + hf * 8 + j;
      const float* pb2 = pT + ((size_t)co << 12) + pix;
      #pragma unroll
      for (int i = 0; i < 8; ++i) {
        float pv = pb2[(size_t)i * 1048576];
        if (ng == 0) pp[i] += pv * pv;
        pt[0][i] += tv[0][j] * pv;
        pt[1][i] += tv[1][j] * pv;
      }
      tt[0] += tv[0][j] * tv[0][j];
      tt[1] += tv[1][j] * tv[1][j];
    }
  }
  // wave-level butterfly reduction (64 lanes)
  #pragma unroll
  for (int m = 1; m < 64; m <<= 1) {
    #pragma unroll
    for (int k = 0; k < 2; ++k) {
      tt[k] += __shfl_xor(tt[k], m);
      #pragma unroll
      for (int i = 0; i < 8; ++i) pt[k][i] += __shfl_xor(pt[k][i], m);
    }
    #pragma unroll
    for (int i = 0; i < 8; ++i) pp[i] += __shfl_xor(pp[i], m);
  }
  if (c == 0) {
    #pragma unroll
    for (int k = 0; k < 2; ++k) {
      int n = ng * 2 + k;
      atomicAdd(&accums[8 + n], tt[k]);
      #pragma unroll
      for (int i = 0; i < 8; ++i) atomicAdd(&accums[16 + i * 8 + n], pt[k][i]);
    }
    if (ng == 0) {
      #pragma unroll
      for (int i = 0; i < 8; ++i) atomicAdd(&accums[i], pp[i]);
    }
  }
}

// ---------------------------------------------------------------------------
// k4: 8x8 logsumexp finisher.
// ---------------------------------------------------------------------------
__global__ void k4_final(const float* __restrict__ accums, float* __restrict__ out)
{
  if (threadIdx.x == 0 && blockIdx.x == 0) {
    double logits[8][8];
    for (int i = 0; i < 8; ++i)
      for (int j = 0; j < 8; ++j) {
        double sq = (double)accums[i] + (double)accums[8 + j]
                    - 2.0 * (double)accums[16 + i * 8 + j];
        logits[i][j] = -0.5 * sq / 64.0;
      }
    double ce = 0.0;
    for (int i = 0; i < 8; ++i) {
      double m = logits[i][0];
      for (int j = 1; j < 8; ++j) m = logits[i][j] > m ? logits[i][j] : m;
      double s = 0.0;
      for (int j = 0; j < 8; ++j) s += exp(logits[i][j] - m);
      ce += (m + log(s)) - logits[i][i];
    }
    ce /= 8.0;
    out[0] = (float)(ce * (2.0 * 64.0) / 8.0 * 2e-05);
  }
}

// ---------------------------------------------------------------------------
extern "C" void kernel_launch(void* const* d_in, const int* in_sizes, int n_in,
                              void* d_out, int out_size, void* d_ws, size_t ws_size,
                              hipStream_t stream)
{
  const float* preds_S = (const float*)d_in[0];
  const float* preds_T = (const float*)d_in[1];
  const float* W_align = (const float*)d_in[2];
  const float* b_align = (const float*)d_in[3];
  const float* W_gen1  = (const float*)d_in[4];
  const float* b_gen1  = (const float*)d_in[5];
  const float* W_gen2  = (const float*)d_in[6];
  const float* b_gen2  = (const float*)d_in[7];
  float* out = (float*)d_out;

  char* wsb = (char*)d_ws;
  u16* masked = (u16*)wsb;                          // 17,842,176 B
  u16* t1     = (u16*)(wsb + 17842176);             // 17,842,176 B
  u16* t2     = (u16*)(wsb + 35684352);             // 17,842,176 B (no zero needed)
  u16* Wsw1   = (u16*)(wsb + 53526528);             //  1,179,648 B
  u16* Wsw2   = (u16*)(wsb + 54706176);             //  1,179,648 B
  float* accums = (float*)(wsb + 55885824);         //        320 B

  hipMemsetAsync(wsb, 0, 35684352, stream);         // masked + t1 (zero borders)
  hipMemsetAsync(accums, 0, 320, stream);

  kwc<<<288, 256, 0, stream>>>(W_gen1, Wsw1);
  kwc<<<288, 256, 0, stream>>>(W_gen2, Wsw2);
  k1<<<8192, 256, 0, stream>>>(preds_S, W_align, b_align, masked);
  kconv<1><<<1024, 128, 0, stream>>>(masked, Wsw1, b_gen1, t1);
  kconv<0><<<1024, 128, 0, stream>>>(t1, Wsw2, b_gen2, t2);
  kbmc<<<512, 256, 0, stream>>>(t2, preds_T, accums);
  k4_final<<<1, 64, 0, stream>>>(accums, out);
}

// Round 3
// 446.869 us; speedup vs baseline: 2.8377x; 1.2627x over previous
//
#include <hip/hip_runtime.h>

typedef unsigned short u16;
typedef short short8 __attribute__((ext_vector_type(8)));
typedef unsigned short ushort8 __attribute__((ext_vector_type(8)));
typedef float floatx16 __attribute__((ext_vector_type(16)));

// ---- sizes (ushort units unless noted) ----
// masked/t1 layout: [n 8][cg 16][half 2][r 66][c 66][j 8] bf16 (padded, swizzled)
#define PLANE8   34848          // 66*66*8
#define NSTRIDE  1115136        // 16*2*PLANE8
// t2 layout: [n 8][co 256][pix 4096] bf16 (plane, matches preds_T flat index)
// Wsw layout: [cg 16][ct 4][d 1152][j 8] bf16 ; d = tap*128 + sc*64 + cihalf*32 + colow

__device__ __forceinline__ u16 f2b(float f) {
  unsigned u = __builtin_bit_cast(unsigned, f);
  return (u16)((u + 0x7FFFu + ((u >> 16) & 1u)) >> 16);
}
__device__ __forceinline__ float b2f(u16 b) {
  return __builtin_bit_cast(float, ((unsigned)b) << 16);
}

typedef const __attribute__((address_space(1))) unsigned int* gptr_t;
typedef __attribute__((address_space(3))) unsigned int* sptr_t;

// ---------------------------------------------------------------------------
// k1: 1x1 conv + checkerboard mask (fp32 math), swizzled bf16 out.
// grid 1024 = n(8) x cog(32: 8 co each) x pixb(4); thread: 8 co x 4 pix.
// Reuses each loaded S float4 for 8 output channels -> 8x less L2 traffic.
// ---------------------------------------------------------------------------
__global__ __launch_bounds__(256) void k1(const float* __restrict__ pS,
    const float* __restrict__ Wa, const float* __restrict__ ba,
    u16* __restrict__ mk)
{
  __shared__ float wl[1024];   // [ci 128][k 8]
  int b = blockIdx.x;
  int pb = b & 3, cog = (b >> 2) & 31, n = b >> 7;
  int t = threadIdx.x;
  for (int i = t; i < 1024; i += 256) {
    int ci = i >> 3, k = i & 7;
    wl[i] = Wa[cog * 1024 + k * 128 + ci];
  }
  __syncthreads();

  int pix0 = pb * 1024 + t * 4;
  const float* sp = pS + (((size_t)n * 128) << 12) + pix0;

  float acc[8][4];
  #pragma unroll
  for (int k = 0; k < 8; ++k)
    #pragma unroll
    for (int q = 0; q < 4; ++q) acc[k][q] = 0.f;

  for (int ci = 0; ci < 128; ++ci) {
    float4 s = *(const float4*)(sp + ((size_t)ci << 12));
    float4 w0 = *(const float4*)(wl + ci * 8);
    float4 w1 = *(const float4*)(wl + ci * 8 + 4);
    float wv[8] = {w0.x, w0.y, w0.z, w0.w, w1.x, w1.y, w1.z, w1.w};
    #pragma unroll
    for (int k = 0; k < 8; ++k) {
      acc[k][0] += s.x * wv[k];
      acc[k][1] += s.y * wv[k];
      acc[k][2] += s.z * wv[k];
      acc[k][3] += s.w * wv[k];
    }
  }

  float bias[8];
  #pragma unroll
  for (int k = 0; k < 8; ++k) bias[k] = ba[cog * 8 + k];
  int h = pix0 >> 6, w = pix0 & 63;
  u16* base = mk + (size_t)n * NSTRIDE + (size_t)cog * PLANE8
              + ((size_t)(h + 1) * 66 + (w + 1)) * 8;
  #pragma unroll
  for (int q = 0; q < 4; ++q) {
    float msk = (float)((h + w + q) & 1);
    short8 v;
    #pragma unroll
    for (int k = 0; k < 8; ++k)
      v[k] = (short)f2b((acc[k][q] + bias[k]) * msk);
    *(short8*)(base + q * 8) = v;
  }
}

// ---------------------------------------------------------------------------
// kwc: convert/swizzle 3x3 weights fp32 [co][ci][3][3] -> Wsw bf16.
// ---------------------------------------------------------------------------
__global__ __launch_bounds__(256) void kwc(const float* __restrict__ W,
                                           u16* __restrict__ D)
{
  int cid = blockIdx.x * 256 + threadIdx.x;        // < 73728
  int d = cid % 1152, ctcg = cid / 1152;
  int ct = ctcg & 3, cg = ctcg >> 2;
  int colow = d & 31, cihalf = (d >> 5) & 1, sc = (d >> 6) & 1, tap = d >> 7;
  int co = ct * 64 + sc * 32 + colow;
  short8 v;
  #pragma unroll
  for (int jj = 0; jj < 8; ++jj) {
    int ci = cg * 16 + cihalf * 8 + jj;
    v[jj] = (short)f2b(W[((size_t)(co * 256 + ci)) * 9 + tap]);
  }
  *(short8*)&D[(size_t)cid * 8] = v;
}

// ---------------------------------------------------------------------------
// kconv: 3x3 conv 256->256 via bf16 MFMA implicit GEMM.
// grid 1024 = n(8) x ct(4) x rowtile(32); block 128 threads = 2 waves.
// MODE 0: +bias, relu, swizzled padded store (gen1)
// MODE 1: +bias, LDS-transpose, plane store [n][co][4096] (gen2)
// ---------------------------------------------------------------------------
template <int MODE>
__global__ __launch_bounds__(128) void kconv(
    const u16* __restrict__ IN, const u16* __restrict__ WS,
    const float* __restrict__ bg, u16* __restrict__ OUT)
{
  __shared__ __align__(16) u16 Lin[4352];             //  8704 B (staging uses 4224)
  __shared__ __align__(16) u16 Lw[1152 * 8];          // 18432 B

  int b = blockIdx.x;
  int rt = b & 31, ct = (b >> 5) & 3, n = b >> 7;
  int h0 = rt * 2;
  int t = threadIdx.x;
  int wid = t >> 6, lane = t & 63;
  int hf = lane >> 5, ml = lane & 31;

  int in_goff[5];
  #pragma unroll
  for (int k = 0; k < 5; ++k) {
    int sidx = wid + 2 * k;
    int d = sidx * 64 + lane;
    if (sidx < 9 && d < 528) {
      int ihalf = d / 264, rem = d - ihalf * 264;
      int rr = rem / 66, c = rem - rr * 66;
      in_goff[k] = ihalf * PLANE8 + ((h0 + rr) * 66 + c) * 8;
    } else in_goff[k] = -1;
  }

  const u16* inb = IN + (size_t)n * NSTRIDE;
  const u16* wg  = WS + (size_t)ct * 1152 * 8;

  floatx16 acc00, acc01, acc10, acc11;
  #pragma unroll
  for (int i = 0; i < 16; ++i) { acc00[i] = 0.f; acc01[i] = 0.f; acc10[i] = 0.f; acc11[i] = 0.f; }

  const short8* LinV = (const short8*)Lin;
  const short8* LwV  = (const short8*)Lw;

  for (int cg = 0; cg < 16; ++cg) {
    #pragma unroll
    for (int k = 0; k < 9; ++k) {
      int sidx = wid + 2 * k;
      const u16* src = wg + (size_t)cg * 36864 + (size_t)(sidx * 64 + lane) * 8;
      __builtin_amdgcn_global_load_lds((gptr_t)(const void*)src,
                                       (sptr_t)(void*)(Lw + sidx * 512), 16, 0, 0);
    }
    #pragma unroll
    for (int k = 0; k < 5; ++k) {
      if (in_goff[k] >= 0) {
        int sidx = wid + 2 * k;
        const u16* src = inb + (size_t)cg * 69696 + in_goff[k];
        __builtin_amdgcn_global_load_lds((gptr_t)(const void*)src,
                                         (sptr_t)(void*)(Lin + sidx * 512), 16, 0, 0);
      }
    }
    __syncthreads();

    #pragma unroll
    for (int dr = 0; dr < 3; ++dr) {
      int rbase = (hf * 4 + (wid + dr)) * 66;
      #pragma unroll
      for (int dc = 0; dc < 3; ++dc) {
        int tap = dr * 3 + dc;
        short8 w0 = LwV[(tap * 2 + 0) * 64 + lane];
        short8 w1 = LwV[(tap * 2 + 1) * 64 + lane];
        short8 i0 = LinV[rbase + ml + dc];
        short8 i1 = LinV[rbase + 32 + ml + dc];
        acc00 = __builtin_amdgcn_mfma_f32_32x32x16_bf16(i0, w0, acc00, 0, 0, 0);
        acc01 = __builtin_amdgcn_mfma_f32_32x32x16_bf16(i0, w1, acc01, 0, 0, 0);
        acc10 = __builtin_amdgcn_mfma_f32_32x32x16_bf16(i1, w0, acc10, 0, 0, 0);
        acc11 = __builtin_amdgcn_mfma_f32_32x32x16_bf16(i1, w1, acc11, 0, 0, 0);
      }
    }
    __syncthreads();
  }

  int co0 = ct * 64 + ml, co1 = co0 + 32;
  float bias0 = bg[co0], bias1 = bg[co1];

  if (MODE == 0) {
    // swizzled padded store (feeds the next conv)
    int sb0 = ((co0 >> 4) * 2 + ((co0 >> 3) & 1)) * PLANE8 + ((h0 + wid + 1) * 66 + 1) * 8 + (co0 & 7);
    int sb1 = ((co1 >> 4) * 2 + ((co1 >> 3) & 1)) * PLANE8 + ((h0 + wid + 1) * 66 + 1) * 8 + (co1 & 7);
    u16* ob = OUT + (size_t)n * NSTRIDE;
    #pragma unroll
    for (int reg = 0; reg < 16; ++reg) {
      int m = (reg & 3) + 8 * (reg >> 2) + 4 * hf;
      float v;
      v = acc00[reg] + bias0; v = fmaxf(v, 0.f); ob[sb0 + m * 8] = f2b(v);
      v = acc01[reg] + bias1; v = fmaxf(v, 0.f); ob[sb1 + m * 8] = f2b(v);
      v = acc10[reg] + bias0; v = fmaxf(v, 0.f); ob[sb0 + (32 + m) * 8] = f2b(v);
      v = acc11[reg] + bias1; v = fmaxf(v, 0.f); ob[sb1 + (32 + m) * 8] = f2b(v);
    }
  } else {
    // LDS transpose -> plane store [n][co][pix]; wave wid owns row h0+wid.
    // plane[co_local][pix] u16, stride 68 (u32 stride 34 -> 2-way max = free).
    u16* plane = (u16*)(wid == 0 ? (void*)Lin : (void*)Lw);
    #pragma unroll
    for (int reg = 0; reg < 16; ++reg) {
      int m = (reg & 3) + 8 * (reg >> 2) + 4 * hf;
      plane[ml * 68 + m]             = f2b(acc00[reg] + bias0);
      plane[(32 + ml) * 68 + m]      = f2b(acc01[reg] + bias1);
      plane[ml * 68 + 32 + m]        = f2b(acc10[reg] + bias0);
      plane[(32 + ml) * 68 + 32 + m] = f2b(acc11[reg] + bias1);
    }
    __syncthreads();
    const u16* row = plane + lane * 68;   // co_local = lane
    __align__(16) u16 tmp[64];
    #pragma unroll
    for (int k2 = 0; k2 < 16; ++k2)
      *(ushort4*)(tmp + k2 * 4) = *(const ushort4*)(row + k2 * 4);
    u16* gdst = OUT + (size_t)n * 1048576 + (size_t)(ct * 64 + lane) * 4096
                + (h0 + wid) * 64;
    #pragma unroll
    for (int k2 = 0; k2 < 8; ++k2)
      *(ushort8*)(gdst + k2 * 8) = *(const ushort8*)(tmp + k2 * 8);
  }
}

// ---------------------------------------------------------------------------
// kbmc: fused reduction over d = co*4096+pix (plane layouts match).
// grid 512 x 256 thr = 4 waves/block; wave role (ih, nh) covers a 4x4 (i,n)
// quadrant. Lane loads 4 float4 (pT) + 4 ushort4 (t2) per iter, 8 iters.
// ---------------------------------------------------------------------------
__global__ __launch_bounds__(256) void kbmc(const u16* __restrict__ t2,
    const float* __restrict__ pT, float* __restrict__ accums)
{
  int t = threadIdx.x, lane = t & 63, role = t >> 6;
  int ih = role >> 1, nh = role & 1;

  float pt[4][4], pp[4], tt[4];
  #pragma unroll
  for (int i = 0; i < 4; ++i) {
    pp[i] = 0.f; tt[i] = 0.f;
    #pragma unroll
    for (int j = 0; j < 4; ++j) pt[i][j] = 0.f;
  }

  const float* pb = pT + ((size_t)ih * 4) * 1048576;
  const u16*   tb = t2 + ((size_t)nh * 4) * 1048576;

  for (int k = 0; k < 8; ++k) {
    size_t d0 = ((size_t)(k * 32768 + blockIdx.x * 64 + lane)) * 4;
    float4 p[4], tf[4];
    #pragma unroll
    for (int i = 0; i < 4; ++i)
      p[i] = *(const float4*)(pb + (size_t)i * 1048576 + d0);
    #pragma unroll
    for (int j = 0; j < 4; ++j) {
      ushort4 tv = *(const ushort4*)(tb + (size_t)j * 1048576 + d0);
      tf[j] = make_float4(b2f(tv.x), b2f(tv.y), b2f(tv.z), b2f(tv.w));
    }
    if (nh == 0) {
      #pragma unroll
      for (int i = 0; i < 4; ++i)
        pp[i] += p[i].x * p[i].x + p[i].y * p[i].y + p[i].z * p[i].z + p[i].w * p[i].w;
    }
    if (ih == 0) {
      #pragma unroll
      for (int j = 0; j < 4; ++j)
        tt[j] += tf[j].x * tf[j].x + tf[j].y * tf[j].y + tf[j].z * tf[j].z + tf[j].w * tf[j].w;
    }
    #pragma unroll
    for (int i = 0; i < 4; ++i)
      #pragma unroll
      for (int j = 0; j < 4; ++j)
        pt[i][j] += p[i].x * tf[j].x + p[i].y * tf[j].y
                  + p[i].z * tf[j].z + p[i].w * tf[j].w;
  }

  // 64-lane butterfly reduction of 24 values
  #pragma unroll
  for (int m = 1; m < 64; m <<= 1) {
    #pragma unroll
    for (int i = 0; i < 4; ++i) {
      pp[i] += __shfl_xor(pp[i], m);
      tt[i] += __shfl_xor(tt[i], m);
      #pragma unroll
      for (int j = 0; j < 4; ++j) pt[i][j] += __shfl_xor(pt[i][j], m);
    }
  }
  if (lane == 0) {
    #pragma unroll
    for (int i = 0; i < 4; ++i)
      #pragma unroll
      for (int j = 0; j < 4; ++j)
        atomicAdd(&accums[16 + (ih * 4 + i) * 8 + (nh * 4 + j)], pt[i][j]);
    if (nh == 0) {
      #pragma unroll
      for (int i = 0; i < 4; ++i) atomicAdd(&accums[ih * 4 + i], pp[i]);
    }
    if (ih == 0) {
      #pragma unroll
      for (int j = 0; j < 4; ++j) atomicAdd(&accums[8 + nh * 4 + j], tt[j]);
    }
  }
}

// ---------------------------------------------------------------------------
// k4: 8x8 logsumexp finisher.
// ---------------------------------------------------------------------------
__global__ void k4_final(const float* __restrict__ accums, float* __restrict__ out)
{
  if (threadIdx.x == 0 && blockIdx.x == 0) {
    double logits[8][8];
    for (int i = 0; i < 8; ++i)
      for (int j = 0; j < 8; ++j) {
        double sq = (double)accums[i] + (double)accums[8 + j]
                    - 2.0 * (double)accums[16 + i * 8 + j];
        logits[i][j] = -0.5 * sq / 64.0;
      }
    double ce = 0.0;
    for (int i = 0; i < 8; ++i) {
      double m = logits[i][0];
      for (int j = 1; j < 8; ++j) m = logits[i][j] > m ? logits[i][j] : m;
      double s = 0.0;
      for (int j = 0; j < 8; ++j) s += exp(logits[i][j] - m);
      ce += (m + log(s)) - logits[i][i];
    }
    ce /= 8.0;
    out[0] = (float)(ce * (2.0 * 64.0) / 8.0 * 2e-05);
  }
}

// ---------------------------------------------------------------------------
extern "C" void kernel_launch(void* const* d_in, const int* in_sizes, int n_in,
                              void* d_out, int out_size, void* d_ws, size_t ws_size,
                              hipStream_t stream)
{
  const float* preds_S = (const float*)d_in[0];
  const float* preds_T = (const float*)d_in[1];
  const float* W_align = (const float*)d_in[2];
  const float* b_align = (const float*)d_in[3];
  const float* W_gen1  = (const float*)d_in[4];
  const float* b_gen1  = (const float*)d_in[5];
  const float* W_gen2  = (const float*)d_in[6];
  const float* b_gen2  = (const float*)d_in[7];
  float* out = (float*)d_out;

  char* wsb = (char*)d_ws;
  u16* masked = (u16*)wsb;                          // 17,842,176 B (swizzled padded)
  u16* t1     = (u16*)(wsb + 17842176);             // 17,842,176 B (swizzled padded)
  u16* t2p    = (u16*)(wsb + 35684352);             // 16,777,216 B (plane [n][co][pix])
  u16* Wsw1   = (u16*)(wsb + 53526528);             //  1,179,648 B
  u16* Wsw2   = (u16*)(wsb + 54706176);             //  1,179,648 B
  float* accums = (float*)(wsb + 55885824);         //        320 B

  hipMemsetAsync(wsb, 0, 35684352, stream);         // masked + t1 (zero borders)
  hipMemsetAsync(accums, 0, 320, stream);

  kwc<<<288, 256, 0, stream>>>(W_gen1, Wsw1);
  kwc<<<288, 256, 0, stream>>>(W_gen2, Wsw2);
  k1<<<1024, 256, 0, stream>>>(preds_S, W_align, b_align, masked);
  kconv<0><<<1024, 128, 0, stream>>>(masked, Wsw1, b_gen1, t1);   // relu -> t1
  kconv<1><<<1024, 128, 0, stream>>>(t1, Wsw2, b_gen2, t2p);      // plane -> t2
  kbmc<<<512, 256, 0, stream>>>(t2p, preds_T, accums);
  k4_final<<<1, 64, 0, stream>>>(accums, out);
}

// Round 4
// 258.585 us; speedup vs baseline: 4.9040x; 1.7281x over previous
//
#include <hip/hip_runtime.h>

typedef unsigned short u16;
typedef short short8 __attribute__((ext_vector_type(8)));
typedef unsigned short ushort8 __attribute__((ext_vector_type(8)));
typedef float floatx16 __attribute__((ext_vector_type(16)));

// ---- sizes (ushort units unless noted) ----
// masked/t1 layout: [n 8][cg 16][half 2][r 66][c 66][j 8] bf16 (padded, swizzled)
#define PLANE8   34848          // 66*66*8
#define NSTRIDE  1115136        // 16*2*PLANE8
// t2 layout: [n 8][co 256][pix 4096] bf16 (plane, matches preds_T flat index)
// Wsw layout: [cg 16][ct 4][d 1152][j 8] bf16 ; d = tap*128 + sc*64 + cihalf*32 + colow
// part layout: [slot 96][bid 512] fp32 ; slot: 0..7 pp, 8..15 tt, 16..79 pt(i*8+j)

__device__ __forceinline__ u16 f2b(float f) {
  unsigned u = __builtin_bit_cast(unsigned, f);
  return (u16)((u + 0x7FFFu + ((u >> 16) & 1u)) >> 16);
}
__device__ __forceinline__ float b2f(u16 b) {
  return __builtin_bit_cast(float, ((unsigned)b) << 16);
}

typedef const __attribute__((address_space(1))) unsigned int* gptr_t;
typedef __attribute__((address_space(3))) unsigned int* sptr_t;

// ---------------------------------------------------------------------------
// k1: 1x1 conv + checkerboard mask (fp32 math), swizzled bf16 out.
// grid 1024 = n(8) x cog(32: 8 co each) x pixb(4); thread: 8 co x 4 pix.
// ---------------------------------------------------------------------------
__global__ __launch_bounds__(256) void k1(const float* __restrict__ pS,
    const float* __restrict__ Wa, const float* __restrict__ ba,
    u16* __restrict__ mk)
{
  __shared__ float wl[1024];   // [ci 128][k 8]
  int b = blockIdx.x;
  int pb = b & 3, cog = (b >> 2) & 31, n = b >> 7;
  int t = threadIdx.x;
  for (int i = t; i < 1024; i += 256) {
    int ci = i >> 3, k = i & 7;
    wl[i] = Wa[cog * 1024 + k * 128 + ci];
  }
  __syncthreads();

  int pix0 = pb * 1024 + t * 4;
  const float* sp = pS + (((size_t)n * 128) << 12) + pix0;

  float acc[8][4];
  #pragma unroll
  for (int k = 0; k < 8; ++k)
    #pragma unroll
    for (int q = 0; q < 4; ++q) acc[k][q] = 0.f;

  for (int ci = 0; ci < 128; ++ci) {
    float4 s = *(const float4*)(sp + ((size_t)ci << 12));
    float4 w0 = *(const float4*)(wl + ci * 8);
    float4 w1 = *(const float4*)(wl + ci * 8 + 4);
    float wv[8] = {w0.x, w0.y, w0.z, w0.w, w1.x, w1.y, w1.z, w1.w};
    #pragma unroll
    for (int k = 0; k < 8; ++k) {
      acc[k][0] += s.x * wv[k];
      acc[k][1] += s.y * wv[k];
      acc[k][2] += s.z * wv[k];
      acc[k][3] += s.w * wv[k];
    }
  }

  float bias[8];
  #pragma unroll
  for (int k = 0; k < 8; ++k) bias[k] = ba[cog * 8 + k];
  int h = pix0 >> 6, w = pix0 & 63;
  u16* base = mk + (size_t)n * NSTRIDE + (size_t)cog * PLANE8
              + ((size_t)(h + 1) * 66 + (w + 1)) * 8;
  #pragma unroll
  for (int q = 0; q < 4; ++q) {
    float msk = (float)((h + w + q) & 1);
    short8 v;
    #pragma unroll
    for (int k = 0; k < 8; ++k)
      v[k] = (short)f2b((acc[k][q] + bias[k]) * msk);
    *(short8*)(base + q * 8) = v;
  }
}

// ---------------------------------------------------------------------------
// kwc: convert/swizzle 3x3 weights fp32 [co][ci][3][3] -> Wsw bf16.
// ---------------------------------------------------------------------------
__global__ __launch_bounds__(256) void kwc(const float* __restrict__ W,
                                           u16* __restrict__ D)
{
  int cid = blockIdx.x * 256 + threadIdx.x;        // < 73728
  int d = cid % 1152, ctcg = cid / 1152;
  int ct = ctcg & 3, cg = ctcg >> 2;
  int colow = d & 31, cihalf = (d >> 5) & 1, sc = (d >> 6) & 1, tap = d >> 7;
  int co = ct * 64 + sc * 32 + colow;
  short8 v;
  #pragma unroll
  for (int jj = 0; jj < 8; ++jj) {
    int ci = cg * 16 + cihalf * 8 + jj;
    v[jj] = (short)f2b(W[((size_t)(co * 256 + ci)) * 9 + tap]);
  }
  *(short8*)&D[(size_t)cid * 8] = v;
}

// ---------------------------------------------------------------------------
// kconv: 3x3 conv 256->256 via bf16 MFMA implicit GEMM.
// grid 1024 = n(8) x ct(4) x rowtile(32); block 128 threads = 2 waves.
// MODE 0: +bias, relu, swizzled padded store (gen1)
// MODE 1: +bias, LDS-transpose, plane store [n][co][4096] (gen2)
// ---------------------------------------------------------------------------
template <int MODE>
__global__ __launch_bounds__(128) void kconv(
    const u16* __restrict__ IN, const u16* __restrict__ WS,
    const float* __restrict__ bg, u16* __restrict__ OUT)
{
  __shared__ __align__(16) u16 Lin[4352];             //  8704 B (staging uses 4224)
  __shared__ __align__(16) u16 Lw[1152 * 8];          // 18432 B

  int b = blockIdx.x;
  int rt = b & 31, ct = (b >> 5) & 3, n = b >> 7;
  int h0 = rt * 2;
  int t = threadIdx.x;
  int wid = t >> 6, lane = t & 63;
  int hf = lane >> 5, ml = lane & 31;

  int in_goff[5];
  #pragma unroll
  for (int k = 0; k < 5; ++k) {
    int sidx = wid + 2 * k;
    int d = sidx * 64 + lane;
    if (sidx < 9 && d < 528) {
      int ihalf = d / 264, rem = d - ihalf * 264;
      int rr = rem / 66, c = rem - rr * 66;
      in_goff[k] = ihalf * PLANE8 + ((h0 + rr) * 66 + c) * 8;
    } else in_goff[k] = -1;
  }

  const u16* inb = IN + (size_t)n * NSTRIDE;
  const u16* wg  = WS + (size_t)ct * 1152 * 8;

  floatx16 acc00, acc01, acc10, acc11;
  #pragma unroll
  for (int i = 0; i < 16; ++i) { acc00[i] = 0.f; acc01[i] = 0.f; acc10[i] = 0.f; acc11[i] = 0.f; }

  const short8* LinV = (const short8*)Lin;
  const short8* LwV  = (const short8*)Lw;

  for (int cg = 0; cg < 16; ++cg) {
    #pragma unroll
    for (int k = 0; k < 9; ++k) {
      int sidx = wid + 2 * k;
      const u16* src = wg + (size_t)cg * 36864 + (size_t)(sidx * 64 + lane) * 8;
      __builtin_amdgcn_global_load_lds((gptr_t)(const void*)src,
                                       (sptr_t)(void*)(Lw + sidx * 512), 16, 0, 0);
    }
    #pragma unroll
    for (int k = 0; k < 5; ++k) {
      if (in_goff[k] >= 0) {
        int sidx = wid + 2 * k;
        const u16* src = inb + (size_t)cg * 69696 + in_goff[k];
        __builtin_amdgcn_global_load_lds((gptr_t)(const void*)src,
                                         (sptr_t)(void*)(Lin + sidx * 512), 16, 0, 0);
      }
    }
    __syncthreads();

    #pragma unroll
    for (int dr = 0; dr < 3; ++dr) {
      int rbase = (hf * 4 + (wid + dr)) * 66;
      #pragma unroll
      for (int dc = 0; dc < 3; ++dc) {
        int tap = dr * 3 + dc;
        short8 w0 = LwV[(tap * 2 + 0) * 64 + lane];
        short8 w1 = LwV[(tap * 2 + 1) * 64 + lane];
        short8 i0 = LinV[rbase + ml + dc];
        short8 i1 = LinV[rbase + 32 + ml + dc];
        acc00 = __builtin_amdgcn_mfma_f32_32x32x16_bf16(i0, w0, acc00, 0, 0, 0);
        acc01 = __builtin_amdgcn_mfma_f32_32x32x16_bf16(i0, w1, acc01, 0, 0, 0);
        acc10 = __builtin_amdgcn_mfma_f32_32x32x16_bf16(i1, w0, acc10, 0, 0, 0);
        acc11 = __builtin_amdgcn_mfma_f32_32x32x16_bf16(i1, w1, acc11, 0, 0, 0);
      }
    }
    __syncthreads();
  }

  int co0 = ct * 64 + ml, co1 = co0 + 32;
  float bias0 = bg[co0], bias1 = bg[co1];

  if (MODE == 0) {
    int sb0 = ((co0 >> 4) * 2 + ((co0 >> 3) & 1)) * PLANE8 + ((h0 + wid + 1) * 66 + 1) * 8 + (co0 & 7);
    int sb1 = ((co1 >> 4) * 2 + ((co1 >> 3) & 1)) * PLANE8 + ((h0 + wid + 1) * 66 + 1) * 8 + (co1 & 7);
    u16* ob = OUT + (size_t)n * NSTRIDE;
    #pragma unroll
    for (int reg = 0; reg < 16; ++reg) {
      int m = (reg & 3) + 8 * (reg >> 2) + 4 * hf;
      float v;
      v = acc00[reg] + bias0; v = fmaxf(v, 0.f); ob[sb0 + m * 8] = f2b(v);
      v = acc01[reg] + bias1; v = fmaxf(v, 0.f); ob[sb1 + m * 8] = f2b(v);
      v = acc10[reg] + bias0; v = fmaxf(v, 0.f); ob[sb0 + (32 + m) * 8] = f2b(v);
      v = acc11[reg] + bias1; v = fmaxf(v, 0.f); ob[sb1 + (32 + m) * 8] = f2b(v);
    }
  } else {
    // LDS transpose -> plane store [n][co][4096]; wave wid owns row h0+wid.
    u16* plane = (u16*)(wid == 0 ? (void*)Lin : (void*)Lw);
    #pragma unroll
    for (int reg = 0; reg < 16; ++reg) {
      int m = (reg & 3) + 8 * (reg >> 2) + 4 * hf;
      plane[ml * 68 + m]             = f2b(acc00[reg] + bias0);
      plane[(32 + ml) * 68 + m]      = f2b(acc01[reg] + bias1);
      plane[ml * 68 + 32 + m]        = f2b(acc10[reg] + bias0);
      plane[(32 + ml) * 68 + 32 + m] = f2b(acc11[reg] + bias1);
    }
    __syncthreads();
    const u16* row = plane + lane * 68;   // co_local = lane
    __align__(16) u16 tmp[64];
    #pragma unroll
    for (int k2 = 0; k2 < 16; ++k2)
      *(ushort4*)(tmp + k2 * 4) = *(const ushort4*)(row + k2 * 4);
    u16* gdst = OUT + (size_t)n * 1048576 + (size_t)(ct * 64 + lane) * 4096
                + (h0 + wid) * 64;
    #pragma unroll
    for (int k2 = 0; k2 < 8; ++k2)
      *(ushort8*)(gdst + k2 * 8) = *(const ushort8*)(tmp + k2 * 8);
  }
}

// ---------------------------------------------------------------------------
// kbmc: fused reduction over d (plane layouts match). NO ATOMICS — each wave's
// lane 0 stores its 16-24 partials to part[slot][bid] (disjoint, plain stores).
// grid 512 x 256 thr = 4 waves/block; wave role (ih, nh) = 4x4 (i,n) quadrant.
// ---------------------------------------------------------------------------
__global__ __launch_bounds__(256) void kbmc(const u16* __restrict__ t2,
    const float* __restrict__ pT, float* __restrict__ part)
{
  int t = threadIdx.x, lane = t & 63, role = t >> 6;
  int ih = role >> 1, nh = role & 1;
  int bid = blockIdx.x;

  float pt[4][4], pp[4], tt[4];
  #pragma unroll
  for (int i = 0; i < 4; ++i) {
    pp[i] = 0.f; tt[i] = 0.f;
    #pragma unroll
    for (int j = 0; j < 4; ++j) pt[i][j] = 0.f;
  }

  const float* pb = pT + ((size_t)ih * 4) * 1048576;
  const u16*   tb = t2 + ((size_t)nh * 4) * 1048576;

  for (int k = 0; k < 8; ++k) {
    size_t d0 = ((size_t)(bid * 512 + k * 64 + lane)) * 4;   // block-contiguous
    float4 p[4], tf[4];
    #pragma unroll
    for (int i = 0; i < 4; ++i)
      p[i] = *(const float4*)(pb + (size_t)i * 1048576 + d0);
    #pragma unroll
    for (int j = 0; j < 4; ++j) {
      ushort4 tv = *(const ushort4*)(tb + (size_t)j * 1048576 + d0);
      tf[j] = make_float4(b2f(tv.x), b2f(tv.y), b2f(tv.z), b2f(tv.w));
    }
    if (nh == 0) {
      #pragma unroll
      for (int i = 0; i < 4; ++i)
        pp[i] += p[i].x * p[i].x + p[i].y * p[i].y + p[i].z * p[i].z + p[i].w * p[i].w;
    }
    if (ih == 0) {
      #pragma unroll
      for (int j = 0; j < 4; ++j)
        tt[j] += tf[j].x * tf[j].x + tf[j].y * tf[j].y + tf[j].z * tf[j].z + tf[j].w * tf[j].w;
    }
    #pragma unroll
    for (int i = 0; i < 4; ++i)
      #pragma unroll
      for (int j = 0; j < 4; ++j)
        pt[i][j] += p[i].x * tf[j].x + p[i].y * tf[j].y
                  + p[i].z * tf[j].z + p[i].w * tf[j].w;
  }

  // 64-lane butterfly reduction
  #pragma unroll
  for (int m = 1; m < 64; m <<= 1) {
    #pragma unroll
    for (int i = 0; i < 4; ++i) {
      pp[i] += __shfl_xor(pp[i], m);
      tt[i] += __shfl_xor(tt[i], m);
      #pragma unroll
      for (int j = 0; j < 4; ++j) pt[i][j] += __shfl_xor(pt[i][j], m);
    }
  }
  if (lane == 0) {
    #pragma unroll
    for (int i = 0; i < 4; ++i)
      #pragma unroll
      for (int j = 0; j < 4; ++j)
        part[(size_t)(16 + (ih * 4 + i) * 8 + (nh * 4 + j)) * 512 + bid] = pt[i][j];
    if (nh == 0) {
      #pragma unroll
      for (int i = 0; i < 4; ++i) part[(size_t)(ih * 4 + i) * 512 + bid] = pp[i];
    }
    if (ih == 0) {
      #pragma unroll
      for (int j = 0; j < 4; ++j) part[(size_t)(8 + nh * 4 + j) * 512 + bid] = tt[j];
    }
  }
}

// ---------------------------------------------------------------------------
// kred: 80 blocks x 256 threads; block s reduces part[s][0..512) -> accums[s].
// ---------------------------------------------------------------------------
__global__ __launch_bounds__(256) void kred(const float* __restrict__ part,
                                            float* __restrict__ accums)
{
  __shared__ float r4[4];
  int s = blockIdx.x, t = threadIdx.x, lane = t & 63, wid = t >> 6;
  float v = part[(size_t)s * 512 + t] + part[(size_t)s * 512 + 256 + t];
  #pragma unroll
  for (int m = 1; m < 64; m <<= 1) v += __shfl_xor(v, m);
  if (lane == 0) r4[wid] = v;
  __syncthreads();
  if (t == 0) accums[s] = r4[0] + r4[1] + r4[2] + r4[3];
}

// ---------------------------------------------------------------------------
// k4: 8x8 logsumexp finisher. accums: [0..7] pp, [8..15] tt, [16..79] pt.
// ---------------------------------------------------------------------------
__global__ void k4_final(const float* __restrict__ accums, float* __restrict__ out)
{
  if (threadIdx.x == 0 && blockIdx.x == 0) {
    double logits[8][8];
    for (int i = 0; i < 8; ++i)
      for (int j = 0; j < 8; ++j) {
        double sq = (double)accums[i] + (double)accums[8 + j]
                    - 2.0 * (double)accums[16 + i * 8 + j];
        logits[i][j] = -0.5 * sq / 64.0;
      }
    double ce = 0.0;
    for (int i = 0; i < 8; ++i) {
      double m = logits[i][0];
      for (int j = 1; j < 8; ++j) m = logits[i][j] > m ? logits[i][j] : m;
      double s = 0.0;
      for (int j = 0; j < 8; ++j) s += exp(logits[i][j] - m);
      ce += (m + log(s)) - logits[i][i];
    }
    ce /= 8.0;
    out[0] = (float)(ce * (2.0 * 64.0) / 8.0 * 2e-05);
  }
}

// ---------------------------------------------------------------------------
extern "C" void kernel_launch(void* const* d_in, const int* in_sizes, int n_in,
                              void* d_out, int out_size, void* d_ws, size_t ws_size,
                              hipStream_t stream)
{
  const float* preds_S = (const float*)d_in[0];
  const float* preds_T = (const float*)d_in[1];
  const float* W_align = (const float*)d_in[2];
  const float* b_align = (const float*)d_in[3];
  const float* W_gen1  = (const float*)d_in[4];
  const float* b_gen1  = (const float*)d_in[5];
  const float* W_gen2  = (const float*)d_in[6];
  const float* b_gen2  = (const float*)d_in[7];
  float* out = (float*)d_out;

  char* wsb = (char*)d_ws;
  u16* masked = (u16*)wsb;                          // 17,842,176 B (swizzled padded)
  u16* t1     = (u16*)(wsb + 17842176);             // 17,842,176 B (swizzled padded)
  u16* t2p    = (u16*)(wsb + 35684352);             // 16,777,216 B (plane [n][co][pix])
  u16* Wsw1   = (u16*)(wsb + 52461568);             //  1,179,648 B
  u16* Wsw2   = (u16*)(wsb + 53641216);             //  1,179,648 B
  float* part   = (float*)(wsb + 54820864);         //    196,608 B [96][512]
  float* accums = (float*)(wsb + 55017472);         //        384 B

  hipMemsetAsync(wsb, 0, 35684352, stream);         // masked + t1 (zero borders)

  kwc<<<288, 256, 0, stream>>>(W_gen1, Wsw1);
  kwc<<<288, 256, 0, stream>>>(W_gen2, Wsw2);
  k1<<<1024, 256, 0, stream>>>(preds_S, W_align, b_align, masked);
  kconv<0><<<1024, 128, 0, stream>>>(masked, Wsw1, b_gen1, t1);   // relu -> t1
  kconv<1><<<1024, 128, 0, stream>>>(t1, Wsw2, b_gen2, t2p);      // plane -> t2
  kbmc<<<512, 256, 0, stream>>>(t2p, preds_T, part);
  kred<<<80, 256, 0, stream>>>(part, accums);
  k4_final<<<1, 64, 0, stream>>>(accums, out);
}

// Round 5
// 241.838 us; speedup vs baseline: 5.2436x; 1.0692x over previous
//
#include <hip/hip_runtime.h>

typedef unsigned short u16;
typedef short short8 __attribute__((ext_vector_type(8)));
typedef unsigned short ushort8 __attribute__((ext_vector_type(8)));
typedef float floatx16 __attribute__((ext_vector_type(16)));

// ---- sizes (ushort units unless noted) ----
// masked/t1 layout: [n 8][cg 16][half 2][r 66][c 66][j 8] bf16 (padded, swizzled)
#define PLANE8   34848          // 66*66*8
#define NSTRIDE  1115136        // 16*2*PLANE8
// t2 layout: [n 8][co 256][pix 4096] bf16 (plane, matches preds_T flat index)
// Wsw layout: [cg 16][ct 4][d 1152][j 8] bf16 ; d = tap*128 + sc*64 + cihalf*32 + colow
// part layout: [slot 96][bid 512] fp32 ; slot: 0..7 pp, 8..15 tt, 16..79 pt(i*8+j)

__device__ __forceinline__ u16 f2b(float f) {
  unsigned u = __builtin_bit_cast(unsigned, f);
  return (u16)((u + 0x7FFFu + ((u >> 16) & 1u)) >> 16);
}
__device__ __forceinline__ float b2f(u16 b) {
  return __builtin_bit_cast(float, ((unsigned)b) << 16);
}

typedef const __attribute__((address_space(1))) unsigned int* gptr_t;
typedef __attribute__((address_space(3))) unsigned int* sptr_t;

// ---------------------------------------------------------------------------
// k1: 1x1 conv + checkerboard mask (fp32 math), swizzled bf16 out.
// ---------------------------------------------------------------------------
__global__ __launch_bounds__(256) void k1(const float* __restrict__ pS,
    const float* __restrict__ Wa, const float* __restrict__ ba,
    u16* __restrict__ mk)
{
  __shared__ float wl[1024];   // [ci 128][k 8]
  int b = blockIdx.x;
  int pb = b & 3, cog = (b >> 2) & 31, n = b >> 7;
  int t = threadIdx.x;
  for (int i = t; i < 1024; i += 256) {
    int ci = i >> 3, k = i & 7;
    wl[i] = Wa[cog * 1024 + k * 128 + ci];
  }
  __syncthreads();

  int pix0 = pb * 1024 + t * 4;
  const float* sp = pS + (((size_t)n * 128) << 12) + pix0;

  float acc[8][4];
  #pragma unroll
  for (int k = 0; k < 8; ++k)
    #pragma unroll
    for (int q = 0; q < 4; ++q) acc[k][q] = 0.f;

  for (int ci = 0; ci < 128; ++ci) {
    float4 s = *(const float4*)(sp + ((size_t)ci << 12));
    float4 w0 = *(const float4*)(wl + ci * 8);
    float4 w1 = *(const float4*)(wl + ci * 8 + 4);
    float wv[8] = {w0.x, w0.y, w0.z, w0.w, w1.x, w1.y, w1.z, w1.w};
    #pragma unroll
    for (int k = 0; k < 8; ++k) {
      acc[k][0] += s.x * wv[k];
      acc[k][1] += s.y * wv[k];
      acc[k][2] += s.z * wv[k];
      acc[k][3] += s.w * wv[k];
    }
  }

  float bias[8];
  #pragma unroll
  for (int k = 0; k < 8; ++k) bias[k] = ba[cog * 8 + k];
  int h = pix0 >> 6, w = pix0 & 63;
  u16* base = mk + (size_t)n * NSTRIDE + (size_t)cog * PLANE8
              + ((size_t)(h + 1) * 66 + (w + 1)) * 8;
  #pragma unroll
  for (int q = 0; q < 4; ++q) {
    float msk = (float)((h + w + q) & 1);
    short8 v;
    #pragma unroll
    for (int k = 0; k < 8; ++k)
      v[k] = (short)f2b((acc[k][q] + bias[k]) * msk);
    *(short8*)(base + q * 8) = v;
  }
}

// ---------------------------------------------------------------------------
// kwc: convert/swizzle 3x3 weights fp32 [co][ci][3][3] -> Wsw bf16.
// ---------------------------------------------------------------------------
__global__ __launch_bounds__(256) void kwc(const float* __restrict__ W,
                                           u16* __restrict__ D)
{
  int cid = blockIdx.x * 256 + threadIdx.x;        // < 73728
  int d = cid % 1152, ctcg = cid / 1152;
  int ct = ctcg & 3, cg = ctcg >> 2;
  int colow = d & 31, cihalf = (d >> 5) & 1, sc = (d >> 6) & 1, tap = d >> 7;
  int co = ct * 64 + sc * 32 + colow;
  short8 v;
  #pragma unroll
  for (int jj = 0; jj < 8; ++jj) {
    int ci = cg * 16 + cihalf * 8 + jj;
    v[jj] = (short)f2b(W[((size_t)(co * 256 + ci)) * 9 + tap]);
  }
  *(short8*)&D[(size_t)cid * 8] = v;
}

// ---------------------------------------------------------------------------
// kconv: 3x3 conv 256->256, bf16 MFMA implicit GEMM, 2co x 4pix per wave.
// grid 512 = n(8) x ct(4) x rowtile(16); block 128 thr = 2 waves.
// Block tile: co 64 x (4 rows x 64 cols); wave wid owns rows h0+2*wid+{0,1}.
// Per tap: 2 B-reads + 4 A-reads -> 8 MFMA (0.75 reads/MFMA vs 1.0 before).
// Lin: [half 2][448 chunks] (rows h0-1..h0+4 linearized, 52-chunk tail pad).
// MODE 0: +bias, relu, swizzled padded store (gen1)
// MODE 1: +bias, LDS-transpose, plane store [n][co][4096] (gen2)
// ---------------------------------------------------------------------------
template <int MODE>
__global__ __launch_bounds__(128) void kconv(
    const u16* __restrict__ IN, const u16* __restrict__ WS,
    const float* __restrict__ bg, u16* __restrict__ OUT)
{
  __shared__ __align__(16) u16 Lin[896 * 8];    // 14336 B
  __shared__ __align__(16) u16 Lw[1152 * 8];    // 18432 B

  int b = blockIdx.x;
  int rt = b & 15, ct = (b >> 4) & 3, n = b >> 6;
  int h0 = rt * 4;
  int t = threadIdx.x;
  int wid = t >> 6, lane = t & 63;
  int hf = lane >> 5, ml = lane & 31;

  // Input staging: 14 segs (2 halves x 7), 7 per wave; seg = 2k+wid,
  // half = seg/7, s = seg%7. Per-lane global src (u16): includes +lane*8.
  // Padded-row base h0 (input row h0-1 -> padded row h0). Tail lanes of s=6
  // over-read ~52 chunks past the plane -- lands in later ws regions, and the
  // garbage LDS chunks (idx>=396 per half) are never read by the MFMA loop.
  int in_goff[7];
  int lds_off[7];
  #pragma unroll
  for (int k = 0; k < 7; ++k) {
    int seg = 2 * k + wid;
    int half = seg >= 7 ? 1 : 0;
    int s = seg - half * 7;
    in_goff[k] = half * PLANE8 + (h0 * 66 + s * 64 + lane) * 8;
    lds_off[k] = (half * 448 + s * 64) * 8;
  }

  const u16* inb = IN + (size_t)n * NSTRIDE;
  const u16* wg  = WS + (size_t)ct * 1152 * 8;

  floatx16 acc[2][2][2];   // [row r][colhalf s][co-sub q]
  #pragma unroll
  for (int r = 0; r < 2; ++r)
    #pragma unroll
    for (int s = 0; s < 2; ++s)
      #pragma unroll
      for (int q = 0; q < 2; ++q)
        #pragma unroll
        for (int i = 0; i < 16; ++i) acc[r][s][q][i] = 0.f;

  const short8* LinV = (const short8*)Lin;
  const short8* LwV  = (const short8*)Lw;

  for (int cg = 0; cg < 16; ++cg) {
    // ---- stage weights: 18 segs, 9 per wave ----
    #pragma unroll
    for (int k = 0; k < 9; ++k) {
      int sidx = wid + 2 * k;
      const u16* src = wg + (size_t)cg * 36864 + (size_t)(sidx * 64 + lane) * 8;
      __builtin_amdgcn_global_load_lds((gptr_t)(const void*)src,
                                       (sptr_t)(void*)(Lw + sidx * 512), 16, 0, 0);
    }
    // ---- stage input: 14 segs, 7 per wave ----
    #pragma unroll
    for (int k = 0; k < 7; ++k) {
      const u16* src = inb + (size_t)cg * 69696 + in_goff[k];
      __builtin_amdgcn_global_load_lds((gptr_t)(const void*)src,
                                       (sptr_t)(void*)(Lin + lds_off[k]), 16, 0, 0);
    }
    __syncthreads();

    #pragma unroll
    for (int dr = 0; dr < 3; ++dr) {
      int r0 = hf * 448 + (2 * wid + dr) * 66;       // input row for out-row r=0
      int r1 = r0 + 66;                              // r=1
      #pragma unroll
      for (int dc = 0; dc < 3; ++dc) {
        int tap = dr * 3 + dc;
        short8 w0 = LwV[tap * 128 + lane];
        short8 w1 = LwV[tap * 128 + 64 + lane];
        short8 i00 = LinV[r0 + ml + dc];
        short8 i01 = LinV[r0 + 32 + ml + dc];
        short8 i10 = LinV[r1 + ml + dc];
        short8 i11 = LinV[r1 + 32 + ml + dc];
        acc[0][0][0] = __builtin_amdgcn_mfma_f32_32x32x16_bf16(i00, w0, acc[0][0][0], 0, 0, 0);
        acc[0][0][1] = __builtin_amdgcn_mfma_f32_32x32x16_bf16(i00, w1, acc[0][0][1], 0, 0, 0);
        acc[0][1][0] = __builtin_amdgcn_mfma_f32_32x32x16_bf16(i01, w0, acc[0][1][0], 0, 0, 0);
        acc[0][1][1] = __builtin_amdgcn_mfma_f32_32x32x16_bf16(i01, w1, acc[0][1][1], 0, 0, 0);
        acc[1][0][0] = __builtin_amdgcn_mfma_f32_32x32x16_bf16(i10, w0, acc[1][0][0], 0, 0, 0);
        acc[1][0][1] = __builtin_amdgcn_mfma_f32_32x32x16_bf16(i10, w1, acc[1][0][1], 0, 0, 0);
        acc[1][1][0] = __builtin_amdgcn_mfma_f32_32x32x16_bf16(i11, w0, acc[1][1][0], 0, 0, 0);
        acc[1][1][1] = __builtin_amdgcn_mfma_f32_32x32x16_bf16(i11, w1, acc[1][1][1], 0, 0, 0);
      }
    }
    __syncthreads();
  }

  float bias0 = bg[ct * 64 + ml];        // q=0
  float bias1 = bg[ct * 64 + 32 + ml];   // q=1

  if (MODE == 0) {
    // swizzled padded store; C layout: co = ct*64 + q*32 + ml,
    // pix col p = s*32 + (reg&3)+8*(reg>>2)+4*hf, row o = h0+2*wid+r.
    u16* ob = OUT + (size_t)n * NSTRIDE;
    int co0 = ct * 64 + ml, co1 = co0 + 32;
    int cb0 = ((co0 >> 4) * 2 + ((co0 >> 3) & 1)) * PLANE8 + (co0 & 7);
    int cb1 = ((co1 >> 4) * 2 + ((co1 >> 3) & 1)) * PLANE8 + (co1 & 7);
    #pragma unroll
    for (int r = 0; r < 2; ++r) {
      int rowoff = (h0 + 2 * wid + r + 1) * 66 + 1;
      #pragma unroll
      for (int reg = 0; reg < 16; ++reg) {
        int m = (reg & 3) + 8 * (reg >> 2) + 4 * hf;
        float v;
        v = acc[r][0][0][reg] + bias0; v = fmaxf(v, 0.f); ob[cb0 + (rowoff + m) * 8] = f2b(v);
        v = acc[r][0][1][reg] + bias1; v = fmaxf(v, 0.f); ob[cb1 + (rowoff + m) * 8] = f2b(v);
        v = acc[r][1][0][reg] + bias0; v = fmaxf(v, 0.f); ob[cb0 + (rowoff + 32 + m) * 8] = f2b(v);
        v = acc[r][1][1][reg] + bias1; v = fmaxf(v, 0.f); ob[cb1 + (rowoff + 32 + m) * 8] = f2b(v);
      }
    }
  } else {
    // LDS transpose -> plane [n][co][4096]; per-wave plane 64co x 64col, stride 68.
    u16* plane = (wid == 0) ? Lin : Lw;
    #pragma unroll
    for (int r = 0; r < 2; ++r) {
      __syncthreads();
      #pragma unroll
      for (int reg = 0; reg < 16; ++reg) {
        int m = (reg & 3) + 8 * (reg >> 2) + 4 * hf;
        plane[ml * 68 + m]              = f2b(acc[r][0][0][reg] + bias0);
        plane[(32 + ml) * 68 + m]       = f2b(acc[r][0][1][reg] + bias1);
        plane[ml * 68 + 32 + m]         = f2b(acc[r][1][0][reg] + bias0);
        plane[(32 + ml) * 68 + 32 + m]  = f2b(acc[r][1][1][reg] + bias1);
      }
      __syncthreads();
      const u16* row = plane + lane * 68;   // co_local = lane
      __align__(16) u16 tmp[64];
      #pragma unroll
      for (int k2 = 0; k2 < 16; ++k2)
        *(ushort4*)(tmp + k2 * 4) = *(const ushort4*)(row + k2 * 4);
      u16* gdst = OUT + (size_t)n * 1048576 + (size_t)(ct * 64 + lane) * 4096
                  + (h0 + 2 * wid + r) * 64;
      #pragma unroll
      for (int k2 = 0; k2 < 8; ++k2)
        *(ushort8*)(gdst + k2 * 8) = *(const ushort8*)(tmp + k2 * 8);
    }
  }
}

// ---------------------------------------------------------------------------
// kbmc: fused reduction over d (plane layouts match). No atomics.
// ---------------------------------------------------------------------------
__global__ __launch_bounds__(256) void kbmc(const u16* __restrict__ t2,
    const float* __restrict__ pT, float* __restrict__ part)
{
  int t = threadIdx.x, lane = t & 63, role = t >> 6;
  int ih = role >> 1, nh = role & 1;
  int bid = blockIdx.x;

  float pt[4][4], pp[4], tt[4];
  #pragma unroll
  for (int i = 0; i < 4; ++i) {
    pp[i] = 0.f; tt[i] = 0.f;
    #pragma unroll
    for (int j = 0; j < 4; ++j) pt[i][j] = 0.f;
  }

  const float* pb = pT + ((size_t)ih * 4) * 1048576;
  const u16*   tb = t2 + ((size_t)nh * 4) * 1048576;

  for (int k = 0; k < 8; ++k) {
    size_t d0 = ((size_t)(bid * 512 + k * 64 + lane)) * 4;
    float4 p[4], tf[4];
    #pragma unroll
    for (int i = 0; i < 4; ++i)
      p[i] = *(const float4*)(pb + (size_t)i * 1048576 + d0);
    #pragma unroll
    for (int j = 0; j < 4; ++j) {
      ushort4 tv = *(const ushort4*)(tb + (size_t)j * 1048576 + d0);
      tf[j] = make_float4(b2f(tv.x), b2f(tv.y), b2f(tv.z), b2f(tv.w));
    }
    if (nh == 0) {
      #pragma unroll
      for (int i = 0; i < 4; ++i)
        pp[i] += p[i].x * p[i].x + p[i].y * p[i].y + p[i].z * p[i].z + p[i].w * p[i].w;
    }
    if (ih == 0) {
      #pragma unroll
      for (int j = 0; j < 4; ++j)
        tt[j] += tf[j].x * tf[j].x + tf[j].y * tf[j].y + tf[j].z * tf[j].z + tf[j].w * tf[j].w;
    }
    #pragma unroll
    for (int i = 0; i < 4; ++i)
      #pragma unroll
      for (int j = 0; j < 4; ++j)
        pt[i][j] += p[i].x * tf[j].x + p[i].y * tf[j].y
                  + p[i].z * tf[j].z + p[i].w * tf[j].w;
  }

  #pragma unroll
  for (int m = 1; m < 64; m <<= 1) {
    #pragma unroll
    for (int i = 0; i < 4; ++i) {
      pp[i] += __shfl_xor(pp[i], m);
      tt[i] += __shfl_xor(tt[i], m);
      #pragma unroll
      for (int j = 0; j < 4; ++j) pt[i][j] += __shfl_xor(pt[i][j], m);
    }
  }
  if (lane == 0) {
    #pragma unroll
    for (int i = 0; i < 4; ++i)
      #pragma unroll
      for (int j = 0; j < 4; ++j)
        part[(size_t)(16 + (ih * 4 + i) * 8 + (nh * 4 + j)) * 512 + bid] = pt[i][j];
    if (nh == 0) {
      #pragma unroll
      for (int i = 0; i < 4; ++i) part[(size_t)(ih * 4 + i) * 512 + bid] = pp[i];
    }
    if (ih == 0) {
      #pragma unroll
      for (int j = 0; j < 4; ++j) part[(size_t)(8 + nh * 4 + j) * 512 + bid] = tt[j];
    }
  }
}

// ---------------------------------------------------------------------------
// kred: 80 blocks x 256 threads; block s reduces part[s][0..512) -> accums[s].
// ---------------------------------------------------------------------------
__global__ __launch_bounds__(256) void kred(const float* __restrict__ part,
                                            float* __restrict__ accums)
{
  __shared__ float r4[4];
  int s = blockIdx.x, t = threadIdx.x, lane = t & 63, wid = t >> 6;
  float v = part[(size_t)s * 512 + t] + part[(size_t)s * 512 + 256 + t];
  #pragma unroll
  for (int m = 1; m < 64; m <<= 1) v += __shfl_xor(v, m);
  if (lane == 0) r4[wid] = v;
  __syncthreads();
  if (t == 0) accums[s] = r4[0] + r4[1] + r4[2] + r4[3];
}

// ---------------------------------------------------------------------------
// k4: 8x8 logsumexp finisher, one lane per (i,j) logit; shuffle reductions.
// ---------------------------------------------------------------------------
__global__ void k4_final(const float* __restrict__ accums, float* __restrict__ out)
{
  int t = threadIdx.x;           // 64 threads, lane = i*8 + j
  int i = t >> 3, j = t & 7;
  double pp = accums[i];
  double tt = accums[8 + j];
  double pt = accums[16 + i * 8 + j];
  double logit = -0.5 * (pp + tt - 2.0 * pt) / 64.0;
  // rowwise (over j, within 8-lane groups) logsumexp
  double m = logit;
  #pragma unroll
  for (int s = 1; s < 8; s <<= 1) {
    double o = __shfl_xor(m, s);
    m = o > m ? o : m;
  }
  double e = exp(logit - m);
  #pragma unroll
  for (int s = 1; s < 8; s <<= 1) e += __shfl_xor(e, s);
  double lse = m + log(e);
  double term = (j == i) ? (lse - logit) : 0.0;
  // sum the 8 per-row terms (held on diagonal lanes) across all 64 lanes
  #pragma unroll
  for (int s = 1; s < 64; s <<= 1) term += __shfl_xor(term, s);
  if (t == 0) {
    double ce = term / 8.0;
    out[0] = (float)(ce * (2.0 * 64.0) / 8.0 * 2e-05);
  }
}

// ---------------------------------------------------------------------------
extern "C" void kernel_launch(void* const* d_in, const int* in_sizes, int n_in,
                              void* d_out, int out_size, void* d_ws, size_t ws_size,
                              hipStream_t stream)
{
  const float* preds_S = (const float*)d_in[0];
  const float* preds_T = (const float*)d_in[1];
  const float* W_align = (const float*)d_in[2];
  const float* b_align = (const float*)d_in[3];
  const float* W_gen1  = (const float*)d_in[4];
  const float* b_gen1  = (const float*)d_in[5];
  const float* W_gen2  = (const float*)d_in[6];
  const float* b_gen2  = (const float*)d_in[7];
  float* out = (float*)d_out;

  char* wsb = (char*)d_ws;
  u16* masked = (u16*)wsb;                          // 17,842,176 B (swizzled padded)
  u16* t1     = (u16*)(wsb + 17842176);             // 17,842,176 B (swizzled padded)
  u16* t2p    = (u16*)(wsb + 35684352);             // 16,777,216 B (plane [n][co][pix])
  u16* Wsw1   = (u16*)(wsb + 52461568);             //  1,179,648 B
  u16* Wsw2   = (u16*)(wsb + 53641216);             //  1,179,648 B
  float* part   = (float*)(wsb + 54820864);         //    196,608 B [96][512]
  float* accums = (float*)(wsb + 55017472);         //        384 B

  hipMemsetAsync(wsb, 0, 35684352, stream);         // masked + t1 (zero borders)

  kwc<<<288, 256, 0, stream>>>(W_gen1, Wsw1);
  kwc<<<288, 256, 0, stream>>>(W_gen2, Wsw2);
  k1<<<1024, 256, 0, stream>>>(preds_S, W_align, b_align, masked);
  kconv<0><<<512, 128, 0, stream>>>(masked, Wsw1, b_gen1, t1);    // relu -> t1
  kconv<1><<<512, 128, 0, stream>>>(t1, Wsw2, b_gen2, t2p);       // plane -> t2
  kbmc<<<512, 256, 0, stream>>>(t2p, preds_T, part);
  kred<<<80, 256, 0, stream>>>(part, accums);
  k4_final<<<1, 64, 0, stream>>>(accums, out);
}